// Round 3
// baseline (634.482 us; speedup 1.0000x reference)
//
#include <hip/hip_runtime.h>
#include <cmath>

#define NB 16
#define NL 64
#define NP 512
#define NH 128
#define NG 10
#define ROWS (NB * NL * NP)          // 524288 rows of Interact

// output layout (flat float32, reference return order)
#define OFF_PI    ((size_t)0)
#define OFF_SIGMA ((size_t)5242880)
#define OFF_MU    ((size_t)10485760)
#define OFF_DIST  ((size_t)15728640)
#define OFF_MASK  ((size_t)16252928)

// ---------------------------------------------------------------------------
// Kernel 1: min-distance over 24 atoms + mask application + mask-as-float out
// ---------------------------------------------------------------------------
__global__ __launch_bounds__(256) void k_dist(
    const float* __restrict__ pos_l,   // [B, NL, 3]
    const float* __restrict__ pos_p,   // [B, NP, 24, 3]
    const int*   __restrict__ mask,    // [B, NL, NP]
    float* __restrict__ dist_out,
    float* __restrict__ mask_out)
{
    int idx = blockIdx.x * 256 + threadIdx.x;   // b*NL*NP + l*NP + p
    int p  = idx & (NP - 1);
    int bl = idx >> 9;
    int b  = bl >> 6;

    const float* xl = pos_l + bl * 3;
    float x0 = xl[0], x1 = xl[1], x2 = xl[2];
    float xs = x0 * x0 + x1 * x1 + x2 * x2;

    const float4* yp = (const float4*)(pos_p + ((size_t)(b * NP + p)) * 72);

    float m = 1e30f;
    #pragma unroll
    for (int q = 0; q < 6; ++q) {               // 4 atoms / iter
        float4 v0 = yp[q * 3 + 0];
        float4 v1 = yp[q * 3 + 1];
        float4 v2 = yp[q * 3 + 2];
        float c[12] = {v0.x, v0.y, v0.z, v0.w,
                       v1.x, v1.y, v1.z, v1.w,
                       v2.x, v2.y, v2.z, v2.w};
        #pragma unroll
        for (int a = 0; a < 4; ++a) {
            float yx = c[a * 3 + 0], yy = c[a * 3 + 1], yz = c[a * 3 + 2];
            float d2 = xs + (yx * yx + yy * yy + yz * yz)
                          - 2.0f * (x0 * yx + x1 * yy + x2 * yz);
            float s = (d2 >= 0.0f) ? sqrtf(d2) : 10000.0f;  // NaN -> 10000
            m = fminf(m, s);
        }
    }

    int mk = mask[idx];
    dist_out[idx] = mk ? m : 0.0f;
    mask_out[idx] = mk ? 1.0f : 0.0f;
}

// ---------------------------------------------------------------------------
// Kernel 2: fused 3x GEMV [128 -> 10] + softmax / leaky+clip / leaky
// 4 ROWS PER THREAD: each wave-uniform ds_read_b128 of W feeds 16 FMAs
// (R1's 1-row version fed only 4 -> LDS-pipe-bound at ~164 us).
// W_pi|W_sigma|W_mu packed [128][32] in LDS (pad 30->32), packed per-block.
// ---------------------------------------------------------------------------
__global__ __launch_bounds__(256, 2) void k_gemv(
    const float* __restrict__ X,       // [ROWS, 128]
    const float* __restrict__ Wpi, const float* __restrict__ bpi,
    const float* __restrict__ Wsg, const float* __restrict__ bsg,
    const float* __restrict__ Wmu, const float* __restrict__ bmu,
    float* __restrict__ out_pi,
    float* __restrict__ out_sg,
    float* __restrict__ out_mu)
{
    __shared__ float lw[NH * 32];
    __shared__ float lb[32];
    int tid = threadIdx.x;

    for (int i = tid; i < NH * 32; i += 256) {
        int k = i >> 5, g = i & 31;
        float v = 0.0f;
        if      (g < 10) v = Wpi[k * NG + g];
        else if (g < 20) v = Wsg[k * NG + (g - 10)];
        else if (g < 30) v = Wmu[k * NG + (g - 20)];
        lw[i] = v;
    }
    if (tid < 32) {
        float v = 0.0f;
        if      (tid < 10) v = bpi[tid];
        else if (tid < 20) v = bsg[tid - 10];
        else if (tid < 30) v = bmu[tid - 20];
        lb[tid] = v;
    }
    __syncthreads();

    const float4* lw4 = (const float4*)lw;
    int base = blockIdx.x * 1024 + tid;            // rows: base + r*256

    const float4* xr[4];
    #pragma unroll
    for (int r = 0; r < 4; ++r)
        xr[r] = (const float4*)(X + (size_t)(base + r * 256) * NH);

    float4 acc[4][8];
    {
        float4 bias[8];
        #pragma unroll
        for (int g4 = 0; g4 < 8; ++g4) bias[g4] = ((const float4*)lb)[g4];
        #pragma unroll
        for (int r = 0; r < 4; ++r)
            #pragma unroll
            for (int g4 = 0; g4 < 8; ++g4) acc[r][g4] = bias[g4];
    }

    for (int c = 0; c < 16; ++c) {                 // 8 k-values per chunk
        float4 xa[4], xb[4];
        #pragma unroll
        for (int r = 0; r < 4; ++r) {
            xa[r] = xr[r][c * 2 + 0];
            xb[r] = xr[r][c * 2 + 1];
        }
        #pragma unroll
        for (int kk = 0; kk < 8; ++kk) {
            float hv[4];
            #pragma unroll
            for (int r = 0; r < 4; ++r) {
                const float* xs4 = (kk < 4) ? (const float*)&xa[r] : (const float*)&xb[r];
                hv[r] = xs4[kk & 3];
            }
            const float4* wrow = lw4 + (size_t)(c * 8 + kk) * 8;   // wave-uniform -> broadcast
            #pragma unroll
            for (int g4 = 0; g4 < 8; ++g4) {
                float4 w = wrow[g4];
                #pragma unroll
                for (int r = 0; r < 4; ++r) {
                    acc[r][g4].x = fmaf(hv[r], w.x, acc[r][g4].x);
                    acc[r][g4].y = fmaf(hv[r], w.y, acc[r][g4].y);
                    acc[r][g4].z = fmaf(hv[r], w.z, acc[r][g4].z);
                    acc[r][g4].w = fmaf(hv[r], w.w, acc[r][g4].w);
                }
            }
        }
    }

    #pragma unroll
    for (int r = 0; r < 4; ++r) {
        float a[32];
        #pragma unroll
        for (int g4 = 0; g4 < 8; ++g4) {
            a[g4 * 4 + 0] = acc[r][g4].x; a[g4 * 4 + 1] = acc[r][g4].y;
            a[g4 * 4 + 2] = acc[r][g4].z; a[g4 * 4 + 3] = acc[r][g4].w;
        }
        size_t ro = (size_t)(base + r * 256) * NG;

        // pi = softmax(a[0..9])
        float mx = a[0];
        #pragma unroll
        for (int g = 1; g < NG; ++g) mx = fmaxf(mx, a[g]);
        float e[NG], s = 0.0f;
        #pragma unroll
        for (int g = 0; g < NG; ++g) { e[g] = __expf(a[g] - mx); s += e[g]; }
        float inv = 1.0f / s;
        #pragma unroll
        for (int g = 0; g < NG; ++g) out_pi[ro + g] = e[g] * inv;

        // sigma = clip(leaky(a[10..19]) + 1.1, 1e-6, inf)
        #pragma unroll
        for (int g = 0; g < NG; ++g) {
            float x = a[10 + g];
            float v = (x >= 0.0f ? x : 0.01f * x) + 1.1f;
            out_sg[ro + g] = fmaxf(v, 1e-6f);
        }

        // mu = leaky(a[20..29]) + 1.0
        #pragma unroll
        for (int g = 0; g < NG; ++g) {
            float x = a[20 + g];
            out_mu[ro + g] = (x >= 0.0f ? x : 0.01f * x) + 1.0f;
        }
    }
}

// ---------------------------------------------------------------------------
extern "C" void kernel_launch(void* const* d_in, const int* in_sizes, int n_in,
                              void* d_out, int out_size, void* d_ws, size_t ws_size,
                              hipStream_t stream) {
    const float* pos_l    = (const float*)d_in[0];
    const float* pos_p    = (const float*)d_in[1];
    const float* Interact = (const float*)d_in[2];
    const int*   mask     = (const int*)  d_in[3];
    const float* Wpi      = (const float*)d_in[4];
    const float* bpi      = (const float*)d_in[5];
    const float* Wsg      = (const float*)d_in[6];
    const float* bsg      = (const float*)d_in[7];
    const float* Wmu      = (const float*)d_in[8];
    const float* bmu      = (const float*)d_in[9];

    float* out      = (float*)d_out;
    float* out_pi   = out + OFF_PI;
    float* out_sg   = out + OFF_SIGMA;
    float* out_mu   = out + OFF_MU;
    float* out_dist = out + OFF_DIST;
    float* out_mask = out + OFF_MASK;

    hipLaunchKernelGGL(k_dist, dim3(ROWS / 256), dim3(256), 0, stream,
                       pos_l, pos_p, mask, out_dist, out_mask);
    hipLaunchKernelGGL(k_gemv, dim3(ROWS / 1024), dim3(256), 0, stream,
                       Interact, Wpi, bpi, Wsg, bsg, Wmu, bmu,
                       out_pi, out_sg, out_mu);
}

// Round 4
// 465.560 us; speedup vs baseline: 1.3628x; 1.3628x over previous
//
#include <hip/hip_runtime.h>
#include <cmath>
#include <stdint.h>

#define NH 128
#define NG 10
#define ROWS (16 * 64 * 512)   // 524288 rows of Interact
#define NP 512

// output layout (flat float32, reference return order)
#define OFF_PI    ((size_t)0)
#define OFF_SIGMA ((size_t)5242880)
#define OFF_MU    ((size_t)10485760)
#define OFF_DIST  ((size_t)15728640)
#define OFF_MASK  ((size_t)16252928)

typedef float floatx4 __attribute__((ext_vector_type(4)));
typedef short shortx8 __attribute__((ext_vector_type(8)));

__device__ inline short f2bf(float f) {          // round-to-nearest bf16
    uint32_t u = __float_as_uint(f);
    return (short)((u + 0x8000u) >> 16);
}

// ---------------------------------------------------------------------------
// Kernel 1: min-distance over 24 atoms + mask application + mask-as-float out
// (unchanged from R1; ~10-15 us, pos_p is L2-resident)
// ---------------------------------------------------------------------------
__global__ __launch_bounds__(256) void k_dist(
    const float* __restrict__ pos_l,   // [B, NL, 3]
    const float* __restrict__ pos_p,   // [B, NP, 24, 3]
    const int*   __restrict__ mask,    // [B, NL, NP]
    float* __restrict__ dist_out,
    float* __restrict__ mask_out)
{
    int idx = blockIdx.x * 256 + threadIdx.x;   // b*NL*NP + l*NP + p
    int p  = idx & (NP - 1);
    int bl = idx >> 9;
    int b  = bl >> 6;

    const float* xl = pos_l + bl * 3;
    float x0 = xl[0], x1 = xl[1], x2 = xl[2];
    float xs = x0 * x0 + x1 * x1 + x2 * x2;

    const float4* yp = (const float4*)(pos_p + ((size_t)(b * NP + p)) * 72);

    float m = 1e30f;
    #pragma unroll
    for (int q = 0; q < 6; ++q) {               // 4 atoms / iter
        float4 v0 = yp[q * 3 + 0];
        float4 v1 = yp[q * 3 + 1];
        float4 v2 = yp[q * 3 + 2];
        float c[12] = {v0.x, v0.y, v0.z, v0.w,
                       v1.x, v1.y, v1.z, v1.w,
                       v2.x, v2.y, v2.z, v2.w};
        #pragma unroll
        for (int a = 0; a < 4; ++a) {
            float yx = c[a * 3 + 0], yy = c[a * 3 + 1], yz = c[a * 3 + 2];
            float d2 = xs + (yx * yx + yy * yy + yz * yz)
                          - 2.0f * (x0 * yx + x1 * yy + x2 * yz);
            float s = (d2 >= 0.0f) ? sqrtf(d2) : 10000.0f;  // NaN -> 10000
            m = fminf(m, s);
        }
    }

    int mk = mask[idx];
    dist_out[idx] = mk ? m : 0.0f;
    mask_out[idx] = mk ? 1.0f : 0.0f;
}

// ---------------------------------------------------------------------------
// Kernel 2: MFMA GEMM  C[M=524288, N=32] = X[M,128] * Wpacked[128,32]
// + fused softmax / leaky+clip / leaky epilogue.
// Block = 128 threads (2 waves), 128-row tile, K in 4 chunks of 32 cols
// (128 B/row staging = fully coalesced), double-buffered LDS, pad 36 f32/row.
// B-fragments (bf16 W) live in registers for the whole block.
// ---------------------------------------------------------------------------
#define MT  128
#define PAD 36

__global__ __launch_bounds__(128, 2) void k_gemv(
    const float* __restrict__ X,       // [ROWS, 128]
    const float* __restrict__ Wpi, const float* __restrict__ bpi,
    const float* __restrict__ Wsg, const float* __restrict__ bsg,
    const float* __restrict__ Wmu, const float* __restrict__ bmu,
    float* __restrict__ out_pi,
    float* __restrict__ out_sg,
    float* __restrict__ out_mu)
{
    __shared__ float lds[2 * MT * PAD];          // 36,864 B -> 4 blocks/CU
    const int tid  = threadIdx.x;                // 0..127
    const int wave = tid >> 6;                   // 0..1
    const int lane = tid & 63;
    const int quad = lane >> 4;                  // 0..3
    const int l16  = lane & 15;
    const int row0 = blockIdx.x * MT;

    // ---- B fragments from global (W is 16 KB, L2-resident; once per block)
    // frag (ks, nt) element j:  k = ks*32 + quad*8 + j ,  n = nt*16 + l16
    // packed n: 0..9 = pi, 10..19 = sigma, 20..29 = mu, 30..31 = 0
    shortx8 bfrag[4][2];
    #pragma unroll
    for (int nt = 0; nt < 2; ++nt) {
        int n = nt * 16 + l16;
        const float* Wm = nullptr; int g = 0;
        if      (n < 10) { Wm = Wpi; g = n; }
        else if (n < 20) { Wm = Wsg; g = n - 10; }
        else if (n < 30) { Wm = Wmu; g = n - 20; }
        #pragma unroll
        for (int ks = 0; ks < 4; ++ks) {
            shortx8 f;
            #pragma unroll
            for (int j = 0; j < 8; ++j) {
                int k = ks * 32 + quad * 8 + j;
                float w = Wm ? Wm[k * NG + g] : 0.0f;
                f[j] = f2bf(w);
            }
            bfrag[ks][nt] = f;
        }
    }

    floatx4 acc[4][2];
    #pragma unroll
    for (int mt = 0; mt < 4; ++mt)
        #pragma unroll
        for (int nt = 0; nt < 2; ++nt)
            acc[mt][nt] = (floatx4){0.f, 0.f, 0.f, 0.f};

    const floatx4* Xg = (const floatx4*)X;
    floatx4 stg[8];

    // prologue: stage ks=0 into buf0   (f = it*128+tid: row=f>>3, col4=f&7 ->
    // 8 consecutive lanes read 128 B contiguous -> perfect coalescing)
    #pragma unroll
    for (int it = 0; it < 8; ++it) {
        int f = it * 128 + tid, r = f >> 3, c4 = f & 7;
        stg[it] = Xg[(size_t)(row0 + r) * 32 + c4];
    }
    #pragma unroll
    for (int it = 0; it < 8; ++it) {
        int f = it * 128 + tid, r = f >> 3, c4 = f & 7;
        *(floatx4*)&lds[r * PAD + c4 * 4] = stg[it];
    }
    __syncthreads();

    for (int ks = 0; ks < 4; ++ks) {
        const float* cur = lds + (ks & 1) * (MT * PAD);
        if (ks < 3) {                             // prefetch next chunk
            #pragma unroll
            for (int it = 0; it < 8; ++it) {
                int f = it * 128 + tid, r = f >> 3, c4 = f & 7;
                stg[it] = Xg[(size_t)(row0 + r) * 32 + (ks + 1) * 8 + c4];
            }
        }
        // A fragments (pad 36 -> only 2-way bank aliasing, free) + MFMA
        #pragma unroll
        for (int mt = 0; mt < 4; ++mt) {
            int m = wave * 64 + mt * 16 + l16;
            const floatx4* ap = (const floatx4*)&cur[m * PAD + quad * 8];
            floatx4 a0 = ap[0], a1 = ap[1];       // 8 consecutive k-values f32
            shortx8 af;
            af[0] = f2bf(a0.x); af[1] = f2bf(a0.y);
            af[2] = f2bf(a0.z); af[3] = f2bf(a0.w);
            af[4] = f2bf(a1.x); af[5] = f2bf(a1.y);
            af[6] = f2bf(a1.z); af[7] = f2bf(a1.w);
            acc[mt][0] = __builtin_amdgcn_mfma_f32_16x16x32_bf16(
                             af, bfrag[ks][0], acc[mt][0], 0, 0, 0);
            acc[mt][1] = __builtin_amdgcn_mfma_f32_16x16x32_bf16(
                             af, bfrag[ks][1], acc[mt][1], 0, 0, 0);
        }
        if (ks < 3) {                             // commit prefetch, flip
            float* nxt = lds + ((ks + 1) & 1) * (MT * PAD);
            #pragma unroll
            for (int it = 0; it < 8; ++it) {
                int f = it * 128 + tid, r = f >> 3, c4 = f & 7;
                *(floatx4*)&nxt[r * PAD + c4 * 4] = stg[it];
            }
            __syncthreads();
        }
    }

    // ---- epilogue: acc -> LDS (reuse buf0), per-thread row activations ----
    // C/D layout (m89/m91-verified): col = lane&15, row = quad*4 + reg
    #pragma unroll
    for (int mt = 0; mt < 4; ++mt)
        #pragma unroll
        for (int nt = 0; nt < 2; ++nt)
            #pragma unroll
            for (int i = 0; i < 4; ++i) {
                int rl = wave * 64 + mt * 16 + quad * 4 + i;
                lds[rl * PAD + nt * 16 + l16] = acc[mt][nt][i];
            }
    __syncthreads();

    int row = row0 + tid;
    float a[32];
    {
        const floatx4* cr = (const floatx4*)&lds[tid * PAD];
        #pragma unroll
        for (int g4 = 0; g4 < 8; ++g4) {
            floatx4 v = cr[g4];
            a[g4 * 4 + 0] = v.x; a[g4 * 4 + 1] = v.y;
            a[g4 * 4 + 2] = v.z; a[g4 * 4 + 3] = v.w;
        }
    }
    size_t ro = (size_t)row * NG;

    // pi = softmax(a[0..9] + bpi)
    float t[NG];
    #pragma unroll
    for (int g = 0; g < NG; ++g) t[g] = a[g] + bpi[g];       // uniform s_load
    float mx = t[0];
    #pragma unroll
    for (int g = 1; g < NG; ++g) mx = fmaxf(mx, t[g]);
    float e[NG], s = 0.0f;
    #pragma unroll
    for (int g = 0; g < NG; ++g) { e[g] = __expf(t[g] - mx); s += e[g]; }
    float inv = 1.0f / s;
    #pragma unroll
    for (int g = 0; g < NG; ++g) out_pi[ro + g] = e[g] * inv;

    // sigma = clip(leaky(a[10..19] + bsg) + 1.1, 1e-6, inf)
    #pragma unroll
    for (int g = 0; g < NG; ++g) {
        float x = a[10 + g] + bsg[g];
        float v = (x >= 0.0f ? x : 0.01f * x) + 1.1f;
        out_sg[ro + g] = fmaxf(v, 1e-6f);
    }

    // mu = leaky(a[20..29] + bmu) + 1.0
    #pragma unroll
    for (int g = 0; g < NG; ++g) {
        float x = a[20 + g] + bmu[g];
        out_mu[ro + g] = (x >= 0.0f ? x : 0.01f * x) + 1.0f;
    }
}

// ---------------------------------------------------------------------------
extern "C" void kernel_launch(void* const* d_in, const int* in_sizes, int n_in,
                              void* d_out, int out_size, void* d_ws, size_t ws_size,
                              hipStream_t stream) {
    const float* pos_l    = (const float*)d_in[0];
    const float* pos_p    = (const float*)d_in[1];
    const float* Interact = (const float*)d_in[2];
    const int*   mask     = (const int*)  d_in[3];
    const float* Wpi      = (const float*)d_in[4];
    const float* bpi      = (const float*)d_in[5];
    const float* Wsg      = (const float*)d_in[6];
    const float* bsg      = (const float*)d_in[7];
    const float* Wmu      = (const float*)d_in[8];
    const float* bmu      = (const float*)d_in[9];

    float* out      = (float*)d_out;
    float* out_pi   = out + OFF_PI;
    float* out_sg   = out + OFF_SIGMA;
    float* out_mu   = out + OFF_MU;
    float* out_dist = out + OFF_DIST;
    float* out_mask = out + OFF_MASK;

    hipLaunchKernelGGL(k_dist, dim3(ROWS / 256), dim3(256), 0, stream,
                       pos_l, pos_p, mask, out_dist, out_mask);
    hipLaunchKernelGGL(k_gemv, dim3(ROWS / MT), dim3(128), 0, stream,
                       Interact, Wpi, bpi, Wsg, bsg, Wmu, bmu,
                       out_pi, out_sg, out_mu);
}